// Round 17
// baseline (130.669 us; speedup 1.0000x reference)
//
#include <hip/hip_runtime.h>

typedef float f4 __attribute__((ext_vector_type(4)));
typedef float f32x4 __attribute__((ext_vector_type(4)));
typedef short bf16x8 __attribute__((ext_vector_type(8)));
typedef unsigned short u16x8 __attribute__((ext_vector_type(8)));

static __device__ __forceinline__ unsigned short f2bf(float f) {
    unsigned int x = __builtin_bit_cast(unsigned int, f);
    x = (x + 0x7fffu + ((x >> 16) & 1u)) >> 16;
    return (unsigned short)x;
}

static __device__ __forceinline__ void gll16(const unsigned short* g, unsigned short* l) {
    __builtin_amdgcn_global_load_lds(
        (__attribute__((address_space(1))) void*)(g),
        (__attribute__((address_space(3))) void*)(l), 16, 0, 0);
}

// LDS frag offset (shorts) for row r, true 16B-slot s (involution, both sides)
static __device__ __forceinline__ int fragoff(int r, int s) {
    return r * 32 + ((s ^ ((r >> 1) & 3)) << 3);
}

// XCD-chunked bijective swizzle (nblk % 8 == 0)
static __device__ __forceinline__ int xcd_swz(int raw, int nblk) {
    const int q = nblk >> 3;
    return (raw & 7) * q + (raw >> 3);
}

// ================= stage 1: merged {e,p} pure-bf16 GEMM with in-staging
//                   f32->bf16 conversion + W_out cvt blocks. bf16 out.
struct GJobF {
    const float *A, *W;
    int lda, ldw;
    const float* bias;
    unsigned short* Ch;
    int N, K, nbx;
};

__global__ __launch_bounds__(256, 4) void gemmcvt64(
    GJobF j0, GJobF j1, int nblk0, int nblk1,
    const float* __restrict__ Wo, unsigned short* __restrict__ Wo_h, int nWo8)
{
    __shared__ unsigned short lds[2][2][64 * 32];   // 2 bufs x {A, W} = 16 KB

    const int bid = blockIdx.x;
    const int tid = threadIdx.x;

    if (bid >= nblk0 + nblk1) {
        const int nblkc = (int)gridDim.x - nblk0 - nblk1;
        for (int g = (bid - nblk0 - nblk1) * 256 + tid; g < nWo8; g += nblkc * 256) {
            const int idx = g * 8;
            f4 a = *(const f4*)(Wo + idx);
            f4 b = *(const f4*)(Wo + idx + 4);
            u16x8 hv;
            float s[8] = { a.x, a.y, a.z, a.w, b.x, b.y, b.z, b.w };
            #pragma unroll
            for (int i = 0; i < 8; ++i) hv[i] = f2bf(s[i]);
            *(u16x8*)(Wo_h + idx) = hv;
        }
        return;
    }

    const bool first = bid < nblk0;
    const GJobF J = first ? j0 : j1;
    const int raw = first ? bid : bid - nblk0;
    const int local = xcd_swz(raw, first ? nblk0 : nblk1);
    const int m0 = (local % J.nbx) * 64;
    const int n0 = (local / J.nbx) * 64;

    const int lane = tid & 63;
    const int wid  = tid >> 6;
    const int wr   = wid >> 1, wc = wid & 1;
    const int lrow = lane & 15;
    const int s    = lane >> 4;

    const int row  = tid >> 2, slot = tid & 3;
    const int woff = fragoff(row, slot);
    const float* pA = J.A + (size_t)(m0 + row) * J.lda + slot * 8;
    const float* pW = J.W + (size_t)(n0 + row) * J.ldw + slot * 8;

    f4 ra0, ra1, rw0, rw1;

#define LOADREGS(k0) do { \
    ra0 = *(const f4*)(pA + (k0));     ra1 = *(const f4*)(pA + (k0) + 4); \
    rw0 = *(const f4*)(pW + (k0));     rw1 = *(const f4*)(pW + (k0) + 4); \
} while (0)

#define CVTWRITE(buf) do { \
    u16x8 ha, hw; \
    float sa[8] = { ra0.x, ra0.y, ra0.z, ra0.w, ra1.x, ra1.y, ra1.z, ra1.w }; \
    float sw[8] = { rw0.x, rw0.y, rw0.z, rw0.w, rw1.x, rw1.y, rw1.z, rw1.w }; \
    _Pragma("unroll") \
    for (int i = 0; i < 8; ++i) { \
        ha[i] = f2bf(sa[i]); \
        hw[i] = f2bf(sw[i]); \
    } \
    *(u16x8*)&lds[buf][0][woff] = ha; \
    *(u16x8*)&lds[buf][1][woff] = hw; \
} while (0)

    f32x4 acc[2][2];
    #pragma unroll
    for (int i = 0; i < 2; ++i)
        #pragma unroll
        for (int j = 0; j < 2; ++j) acc[i][j] = (f32x4){0.f, 0.f, 0.f, 0.f};

    const int nt = J.K / 32;

    LOADREGS(0);
    CVTWRITE(0);
    __syncthreads();

    int cur = 0;
    for (int t = 0; t < nt; ++t) {
        if (t + 1 < nt) LOADREGS((t + 1) * 32);

        bf16x8 av[2], wv[2];
        #pragma unroll
        for (int i = 0; i < 2; ++i) {
            const int ra = wr * 32 + i * 16 + lrow;
            const int rw = wc * 32 + i * 16 + lrow;
            av[i] = *(const bf16x8*)&lds[cur][0][fragoff(ra, s)];
            wv[i] = *(const bf16x8*)&lds[cur][1][fragoff(rw, s)];
        }
        #pragma unroll
        for (int i = 0; i < 2; ++i)
            #pragma unroll
            for (int j = 0; j < 2; ++j)
                acc[i][j] = __builtin_amdgcn_mfma_f32_16x16x32_bf16(av[i], wv[j], acc[i][j], 0, 0, 0);

        if (t + 1 < nt) {
            CVTWRITE(cur ^ 1);
            __syncthreads();
            cur ^= 1;
        }
    }
#undef LOADREGS
#undef CVTWRITE

    // epilogue: bf16 out; C/D layout col=lane&15, row=(lane>>4)*4+r
    #pragma unroll
    for (int i = 0; i < 2; ++i) {
        const int rbase = m0 + wr * 32 + i * 16 + (lane >> 4) * 4;
        #pragma unroll
        for (int j = 0; j < 2; ++j) {
            const int col = n0 + wc * 32 + j * 16 + (lane & 15);
            const float bv = J.bias[col];
            #pragma unroll
            for (int r = 0; r < 4; ++r)
                J.Ch[(size_t)(rbase + r) * J.N + col] = f2bf(acc[i][j][r] + bv);
        }
    }
}

// ================= stage 2: merged {X,Y} pure-bf16 GEMM, 64M x 128N tile,
//                   2-buf DMA staging, XCD swizzle, f32 out.
struct GJob {
    const unsigned short *A, *W;
    int lda, ldw;
    const float* bias;
    float* Cf;
    int N, K, nbx;
};

__global__ __launch_bounds__(256, 4) void gemm64x128(GJob j0, GJob j1, int nblk0)
{
    // per buf: A 64x32 (@0) + W 128x32 (@2048) shorts = 12 KB; 2 bufs = 24 KB
    __shared__ unsigned short lds[2][6144];

    const bool first = (int)blockIdx.x < nblk0;
    const GJob J = first ? j0 : j1;
    const int raw  = first ? (int)blockIdx.x : (int)blockIdx.x - nblk0;
    const int nblk = first ? nblk0 : ((int)gridDim.x - nblk0);
    const int local = xcd_swz(raw, nblk);   // m-fastest: XCD shares W n-panel
    const int m0 = (local % J.nbx) * 64;
    const int n0 = (local / J.nbx) * 128;

    const int tid  = threadIdx.x;
    const int lane = tid & 63;
    const int wid  = tid >> 6;
    const int wr   = wid >> 1, wc = wid & 1;
    const int lrow = lane & 15;
    const int s    = lane >> 4;

    // DMA staging (3 per wave per step): A rows wid*16.., W rows wid*32..
    const int arow  = wid * 16 + (lane >> 2);
    const int aslot = (lane & 3) ^ ((arow >> 1) & 3);
    const size_t gA = (size_t)(m0 + arow) * J.lda + aslot * 8;
    const int wrow0 = wid * 32 + (lane >> 2);
    const int wrow1 = wrow0 + 16;
    const int wsl0  = (lane & 3) ^ ((wrow0 >> 1) & 3);
    const int wsl1  = (lane & 3) ^ ((wrow1 >> 1) & 3);
    const size_t gW0 = (size_t)(n0 + wrow0) * J.ldw + wsl0 * 8;
    const size_t gW1 = (size_t)(n0 + wrow1) * J.ldw + wsl1 * 8;

#define STAGE(buf, k0) do { \
    gll16(J.A + gA + (k0),  &lds[buf][wid * 512]); \
    gll16(J.W + gW0 + (k0), &lds[buf][2048 + wid * 1024]); \
    gll16(J.W + gW1 + (k0), &lds[buf][2048 + wid * 1024 + 512]); \
} while (0)

    f32x4 acc[2][4];
    #pragma unroll
    for (int i = 0; i < 2; ++i)
        #pragma unroll
        for (int j = 0; j < 4; ++j) acc[i][j] = (f32x4){0.f, 0.f, 0.f, 0.f};

    const int nt = J.K / 32;

    STAGE(0, 0);
    asm volatile("s_waitcnt vmcnt(0)" ::: "memory");
    __syncthreads();

    int cur = 0;
    for (int t = 0; t < nt; ++t) {
        if (t + 1 < nt) STAGE(cur ^ 1, (t + 1) * 32);

        bf16x8 av[2], wv[4];
        #pragma unroll
        for (int i = 0; i < 2; ++i) {
            const int ra = wr * 32 + i * 16 + lrow;
            av[i] = *(const bf16x8*)&lds[cur][fragoff(ra, s)];
        }
        #pragma unroll
        for (int j = 0; j < 4; ++j) {
            const int rw = wc * 64 + j * 16 + lrow;    // 0..127
            wv[j] = *(const bf16x8*)&lds[cur][2048 + fragoff(rw, s)];
        }
        #pragma unroll
        for (int i = 0; i < 2; ++i)
            #pragma unroll
            for (int j = 0; j < 4; ++j)
                acc[i][j] = __builtin_amdgcn_mfma_f32_16x16x32_bf16(av[i], wv[j], acc[i][j], 0, 0, 0);

        if (t + 1 < nt) {
            asm volatile("s_waitcnt vmcnt(0)" ::: "memory");
            __syncthreads();
            cur ^= 1;
        }
    }
#undef STAGE

    #pragma unroll
    for (int i = 0; i < 2; ++i) {
        const int rbase = m0 + wr * 32 + i * 16 + (lane >> 4) * 4;
        #pragma unroll
        for (int j = 0; j < 4; ++j) {
            const int col = n0 + wc * 64 + j * 16 + (lane & 15);
            const float bv = J.bias ? J.bias[col] : 0.f;
            #pragma unroll
            for (int r = 0; r < 4; ++r)
                J.Cf[(size_t)(rbase + r) * J.N + col] = acc[i][j][r] + bv;
        }
    }
}

// ================= stage 3: out[(b,t),u,:] = X[(b,t),:] + Y[(b,u),:]
//   A/B vs R16: plain stores (fill-kernel path) instead of nontemporal,
//   deeper unroll for store-queue depth. Everything else identical.
__global__ __launch_bounds__(256) void bcast_kernel(
    const float* __restrict__ X, const float* __restrict__ Y,
    float* __restrict__ out, int T, int U)
{
    const int Vq  = 256;           // 1024 / 4
    const int bt  = blockIdx.x;
    const int b   = bt / T;
    const int tid = threadIdx.x;

    const f4* X4 = (const f4*)X;
    const f4* Y4 = (const f4*)Y + (size_t)b * U * Vq;
    f4* O4 = (f4*)out + (size_t)bt * U * Vq;

    f4 x = X4[(size_t)bt * Vq + tid];
    #pragma unroll 8
    for (int u = 0; u < U; ++u) {
        f4 y = Y4[u * Vq + tid];
        f4 r = { x.x + y.x, x.y + y.y, x.z + y.z, x.w + y.w };
        O4[u * Vq + tid] = r;
    }
}

extern "C" void kernel_launch(void* const* d_in, const int* in_sizes, int n_in,
                              void* d_out, int out_size, void* d_ws, size_t ws_size,
                              hipStream_t stream) {
    (void)in_sizes; (void)n_in; (void)out_size; (void)ws_size;

    const int B = 8, T = 256, U = 64;
    const int ENC = 512, DEC = 640, J = 512, V = 1024;
    const int MT = B * T;   // 2048
    const int MU = B * U;   // 512

    const float* enc    = (const float*)d_in[0];
    const float* pred   = (const float*)d_in[1];
    const float* W_enc  = (const float*)d_in[2];
    const float* b_enc  = (const float*)d_in[3];
    const float* W_pred = (const float*)d_in[4];
    const float* b_pred = (const float*)d_in[5];
    const float* W_out  = (const float*)d_in[6];
    const float* b_out  = (const float*)d_in[7];
    float* out = (float*)d_out;

    const int n_Wo = V * 2 * J;   // 1048576
    const int n_e  = MT * J;      // 1048576
    const int n_p  = MU * J;      // 262144

    unsigned short* w = (unsigned short*)d_ws;
    unsigned short* Wo_h = w;                   // hi plane only
    unsigned short* e_h  = Wo_h + n_Wo;
    unsigned short* p_h  = e_h + n_e;
    float* ws_X = (float*)(p_h + n_p);          // (MT, V)
    float* ws_Y = ws_X + (size_t)MT * V;        // (MU, V)

    // 1) merged e + p pure-bf16 GEMMs (in-staging cvt) + W_out cvt blocks
    GJobF je = { enc,  W_enc,  ENC, ENC, b_enc,  e_h, J, ENC, MT / 64 };
    GJobF jp = { pred, W_pred, DEC, DEC, b_pred, p_h, J, DEC, MU / 64 };
    const int nbe = (MT / 64) * (J / 64);   // 256
    const int nbp = (MU / 64) * (J / 64);   // 64
    const int ncv = 64;
    gemmcvt64<<<nbe + nbp + ncv, 256, 0, stream>>>(
        je, jp, nbe, nbp, W_out, Wo_h, n_Wo / 8);

    // 2) merged X + Y pure-bf16 GEMMs, 64x128 tiles, XCD swizzle, f32 out
    GJob jx = { e_h, Wo_h,     J, 2 * J, b_out,   ws_X, V, J, MT / 64 };
    GJob jy = { p_h, Wo_h + J, J, 2 * J, nullptr, ws_Y, V, J, MU / 64 };
    const int nbx = (MT / 64) * (V / 128);   // 256
    const int nby = (MU / 64) * (V / 128);   // 64
    gemm64x128<<<nbx + nby, 256, 0, stream>>>(jx, jy, nbx);

    // 3) out = X broadcast + Y (plain stores A/B)
    bcast_kernel<<<dim3(B * T), 256, 0, stream>>>(ws_X, ws_Y, out, T, U);
}

// Round 18
// 128.228 us; speedup vs baseline: 1.0190x; 1.0190x over previous
//
#include <hip/hip_runtime.h>

typedef float f4 __attribute__((ext_vector_type(4)));
typedef float f32x4 __attribute__((ext_vector_type(4)));
typedef short bf16x8 __attribute__((ext_vector_type(8)));
typedef unsigned short u16x8 __attribute__((ext_vector_type(8)));

static __device__ __forceinline__ unsigned short f2bf(float f) {
    unsigned int x = __builtin_bit_cast(unsigned int, f);
    x = (x + 0x7fffu + ((x >> 16) & 1u)) >> 16;
    return (unsigned short)x;
}

static __device__ __forceinline__ void gll16(const unsigned short* g, unsigned short* l) {
    __builtin_amdgcn_global_load_lds(
        (__attribute__((address_space(1))) void*)(g),
        (__attribute__((address_space(3))) void*)(l), 16, 0, 0);
}

// LDS frag offset (shorts) for row r, true 16B-slot s (involution, both sides)
static __device__ __forceinline__ int fragoff(int r, int s) {
    return r * 32 + ((s ^ ((r >> 1) & 3)) << 3);
}

// XCD-chunked bijective swizzle (nblk % 8 == 0)
static __device__ __forceinline__ int xcd_swz(int raw, int nblk) {
    const int q = nblk >> 3;
    return (raw & 7) * q + (raw >> 3);
}

// ================= stage 1: merged {e,p} pure-bf16 GEMM with in-staging
//                   f32->bf16 conversion + W_out cvt blocks. bf16 out.
struct GJobF {
    const float *A, *W;
    int lda, ldw;
    const float* bias;
    unsigned short* Ch;
    int N, K, nbx;
};

__global__ __launch_bounds__(256, 4) void gemmcvt64(
    GJobF j0, GJobF j1, int nblk0, int nblk1,
    const float* __restrict__ Wo, unsigned short* __restrict__ Wo_h, int nWo8)
{
    __shared__ unsigned short lds[2][2][64 * 32];   // 2 bufs x {A, W} = 16 KB

    const int bid = blockIdx.x;
    const int tid = threadIdx.x;

    if (bid >= nblk0 + nblk1) {
        const int nblkc = (int)gridDim.x - nblk0 - nblk1;
        for (int g = (bid - nblk0 - nblk1) * 256 + tid; g < nWo8; g += nblkc * 256) {
            const int idx = g * 8;
            f4 a = *(const f4*)(Wo + idx);
            f4 b = *(const f4*)(Wo + idx + 4);
            u16x8 hv;
            float s[8] = { a.x, a.y, a.z, a.w, b.x, b.y, b.z, b.w };
            #pragma unroll
            for (int i = 0; i < 8; ++i) hv[i] = f2bf(s[i]);
            *(u16x8*)(Wo_h + idx) = hv;
        }
        return;
    }

    const bool first = bid < nblk0;
    const GJobF J = first ? j0 : j1;
    const int raw = first ? bid : bid - nblk0;
    const int local = xcd_swz(raw, first ? nblk0 : nblk1);
    const int m0 = (local % J.nbx) * 64;
    const int n0 = (local / J.nbx) * 64;

    const int lane = tid & 63;
    const int wid  = tid >> 6;
    const int wr   = wid >> 1, wc = wid & 1;
    const int lrow = lane & 15;
    const int s    = lane >> 4;

    const int row  = tid >> 2, slot = tid & 3;
    const int woff = fragoff(row, slot);
    const float* pA = J.A + (size_t)(m0 + row) * J.lda + slot * 8;
    const float* pW = J.W + (size_t)(n0 + row) * J.ldw + slot * 8;

    f4 ra0, ra1, rw0, rw1;

#define LOADREGS(k0) do { \
    ra0 = *(const f4*)(pA + (k0));     ra1 = *(const f4*)(pA + (k0) + 4); \
    rw0 = *(const f4*)(pW + (k0));     rw1 = *(const f4*)(pW + (k0) + 4); \
} while (0)

#define CVTWRITE(buf) do { \
    u16x8 ha, hw; \
    float sa[8] = { ra0.x, ra0.y, ra0.z, ra0.w, ra1.x, ra1.y, ra1.z, ra1.w }; \
    float sw[8] = { rw0.x, rw0.y, rw0.z, rw0.w, rw1.x, rw1.y, rw1.z, rw1.w }; \
    _Pragma("unroll") \
    for (int i = 0; i < 8; ++i) { \
        ha[i] = f2bf(sa[i]); \
        hw[i] = f2bf(sw[i]); \
    } \
    *(u16x8*)&lds[buf][0][woff] = ha; \
    *(u16x8*)&lds[buf][1][woff] = hw; \
} while (0)

    f32x4 acc[2][2];
    #pragma unroll
    for (int i = 0; i < 2; ++i)
        #pragma unroll
        for (int j = 0; j < 2; ++j) acc[i][j] = (f32x4){0.f, 0.f, 0.f, 0.f};

    const int nt = J.K / 32;

    LOADREGS(0);
    CVTWRITE(0);
    __syncthreads();

    int cur = 0;
    for (int t = 0; t < nt; ++t) {
        if (t + 1 < nt) LOADREGS((t + 1) * 32);

        bf16x8 av[2], wv[2];
        #pragma unroll
        for (int i = 0; i < 2; ++i) {
            const int ra = wr * 32 + i * 16 + lrow;
            const int rw = wc * 32 + i * 16 + lrow;
            av[i] = *(const bf16x8*)&lds[cur][0][fragoff(ra, s)];
            wv[i] = *(const bf16x8*)&lds[cur][1][fragoff(rw, s)];
        }
        #pragma unroll
        for (int i = 0; i < 2; ++i)
            #pragma unroll
            for (int j = 0; j < 2; ++j)
                acc[i][j] = __builtin_amdgcn_mfma_f32_16x16x32_bf16(av[i], wv[j], acc[i][j], 0, 0, 0);

        if (t + 1 < nt) {
            CVTWRITE(cur ^ 1);
            __syncthreads();
            cur ^= 1;
        }
    }
#undef LOADREGS
#undef CVTWRITE

    // epilogue: bf16 out; C/D layout col=lane&15, row=(lane>>4)*4+r
    #pragma unroll
    for (int i = 0; i < 2; ++i) {
        const int rbase = m0 + wr * 32 + i * 16 + (lane >> 4) * 4;
        #pragma unroll
        for (int j = 0; j < 2; ++j) {
            const int col = n0 + wc * 32 + j * 16 + (lane & 15);
            const float bv = J.bias[col];
            #pragma unroll
            for (int r = 0; r < 4; ++r)
                J.Ch[(size_t)(rbase + r) * J.N + col] = f2bf(acc[i][j][r] + bv);
        }
    }
}

// ================= stage 2: merged {X,Y} pure-bf16 GEMM, 64M x 128N tile,
//                   2-buf DMA staging, XCD swizzle, f32 out.
struct GJob {
    const unsigned short *A, *W;
    int lda, ldw;
    const float* bias;
    float* Cf;
    int N, K, nbx;
};

__global__ __launch_bounds__(256, 4) void gemm64x128(GJob j0, GJob j1, int nblk0)
{
    // per buf: A 64x32 (@0) + W 128x32 (@2048) shorts = 12 KB; 2 bufs = 24 KB
    __shared__ unsigned short lds[2][6144];

    const bool first = (int)blockIdx.x < nblk0;
    const GJob J = first ? j0 : j1;
    const int raw  = first ? (int)blockIdx.x : (int)blockIdx.x - nblk0;
    const int nblk = first ? nblk0 : ((int)gridDim.x - nblk0);
    const int local = xcd_swz(raw, nblk);   // m-fastest: XCD shares W n-panel
    const int m0 = (local % J.nbx) * 64;
    const int n0 = (local / J.nbx) * 128;

    const int tid  = threadIdx.x;
    const int lane = tid & 63;
    const int wid  = tid >> 6;
    const int wr   = wid >> 1, wc = wid & 1;
    const int lrow = lane & 15;
    const int s    = lane >> 4;

    // DMA staging (3 per wave per step): A rows wid*16.., W rows wid*32..
    const int arow  = wid * 16 + (lane >> 2);
    const int aslot = (lane & 3) ^ ((arow >> 1) & 3);
    const size_t gA = (size_t)(m0 + arow) * J.lda + aslot * 8;
    const int wrow0 = wid * 32 + (lane >> 2);
    const int wrow1 = wrow0 + 16;
    const int wsl0  = (lane & 3) ^ ((wrow0 >> 1) & 3);
    const int wsl1  = (lane & 3) ^ ((wrow1 >> 1) & 3);
    const size_t gW0 = (size_t)(n0 + wrow0) * J.ldw + wsl0 * 8;
    const size_t gW1 = (size_t)(n0 + wrow1) * J.ldw + wsl1 * 8;

#define STAGE(buf, k0) do { \
    gll16(J.A + gA + (k0),  &lds[buf][wid * 512]); \
    gll16(J.W + gW0 + (k0), &lds[buf][2048 + wid * 1024]); \
    gll16(J.W + gW1 + (k0), &lds[buf][2048 + wid * 1024 + 512]); \
} while (0)

    f32x4 acc[2][4];
    #pragma unroll
    for (int i = 0; i < 2; ++i)
        #pragma unroll
        for (int j = 0; j < 4; ++j) acc[i][j] = (f32x4){0.f, 0.f, 0.f, 0.f};

    const int nt = J.K / 32;

    STAGE(0, 0);
    asm volatile("s_waitcnt vmcnt(0)" ::: "memory");
    __syncthreads();

    int cur = 0;
    for (int t = 0; t < nt; ++t) {
        if (t + 1 < nt) STAGE(cur ^ 1, (t + 1) * 32);

        bf16x8 av[2], wv[4];
        #pragma unroll
        for (int i = 0; i < 2; ++i) {
            const int ra = wr * 32 + i * 16 + lrow;
            av[i] = *(const bf16x8*)&lds[cur][fragoff(ra, s)];
        }
        #pragma unroll
        for (int j = 0; j < 4; ++j) {
            const int rw = wc * 64 + j * 16 + lrow;    // 0..127
            wv[j] = *(const bf16x8*)&lds[cur][2048 + fragoff(rw, s)];
        }
        #pragma unroll
        for (int i = 0; i < 2; ++i)
            #pragma unroll
            for (int j = 0; j < 4; ++j)
                acc[i][j] = __builtin_amdgcn_mfma_f32_16x16x32_bf16(av[i], wv[j], acc[i][j], 0, 0, 0);

        if (t + 1 < nt) {
            asm volatile("s_waitcnt vmcnt(0)" ::: "memory");
            __syncthreads();
            cur ^= 1;
        }
    }
#undef STAGE

    #pragma unroll
    for (int i = 0; i < 2; ++i) {
        const int rbase = m0 + wr * 32 + i * 16 + (lane >> 4) * 4;
        #pragma unroll
        for (int j = 0; j < 4; ++j) {
            const int col = n0 + wc * 64 + j * 16 + (lane & 15);
            const float bv = J.bias ? J.bias[col] : 0.f;
            #pragma unroll
            for (int r = 0; r < 4; ++r)
                J.Cf[(size_t)(rbase + r) * J.N + col] = acc[i][j][r] + bv;
        }
    }
}

// ================= stage 3: out[(b,t),u,:] = X[(b,t),:] + Y[(b,u),:]
//   Nontemporal stores (R16/R17 A/B: NT beats plain by ~3 us).
__global__ __launch_bounds__(256) void bcast_kernel(
    const float* __restrict__ X, const float* __restrict__ Y,
    float* __restrict__ out, int T, int U)
{
    const int Vq  = 256;           // 1024 / 4
    const int bt  = blockIdx.x;
    const int b   = bt / T;
    const int tid = threadIdx.x;

    const f4* X4 = (const f4*)X;
    const f4* Y4 = (const f4*)Y + (size_t)b * U * Vq;
    f4* O4 = (f4*)out + (size_t)bt * U * Vq;

    f4 x = X4[(size_t)bt * Vq + tid];
    #pragma unroll 4
    for (int u = 0; u < U; ++u) {
        f4 y = Y4[u * Vq + tid];
        f4 r = { x.x + y.x, x.y + y.y, x.z + y.z, x.w + y.w };
        __builtin_nontemporal_store(r, &O4[u * Vq + tid]);
    }
}

extern "C" void kernel_launch(void* const* d_in, const int* in_sizes, int n_in,
                              void* d_out, int out_size, void* d_ws, size_t ws_size,
                              hipStream_t stream) {
    (void)in_sizes; (void)n_in; (void)out_size; (void)ws_size;

    const int B = 8, T = 256, U = 64;
    const int ENC = 512, DEC = 640, J = 512, V = 1024;
    const int MT = B * T;   // 2048
    const int MU = B * U;   // 512

    const float* enc    = (const float*)d_in[0];
    const float* pred   = (const float*)d_in[1];
    const float* W_enc  = (const float*)d_in[2];
    const float* b_enc  = (const float*)d_in[3];
    const float* W_pred = (const float*)d_in[4];
    const float* b_pred = (const float*)d_in[5];
    const float* W_out  = (const float*)d_in[6];
    const float* b_out  = (const float*)d_in[7];
    float* out = (float*)d_out;

    const int n_Wo = V * 2 * J;   // 1048576
    const int n_e  = MT * J;      // 1048576
    const int n_p  = MU * J;      // 262144

    unsigned short* w = (unsigned short*)d_ws;
    unsigned short* Wo_h = w;                   // hi plane only
    unsigned short* e_h  = Wo_h + n_Wo;
    unsigned short* p_h  = e_h + n_e;
    float* ws_X = (float*)(p_h + n_p);          // (MT, V)
    float* ws_Y = ws_X + (size_t)MT * V;        // (MU, V)

    // 1) merged e + p pure-bf16 GEMMs (in-staging cvt) + W_out cvt blocks
    GJobF je = { enc,  W_enc,  ENC, ENC, b_enc,  e_h, J, ENC, MT / 64 };
    GJobF jp = { pred, W_pred, DEC, DEC, b_pred, p_h, J, DEC, MU / 64 };
    const int nbe = (MT / 64) * (J / 64);   // 256
    const int nbp = (MU / 64) * (J / 64);   // 64
    const int ncv = 64;
    gemmcvt64<<<nbe + nbp + ncv, 256, 0, stream>>>(
        je, jp, nbe, nbp, W_out, Wo_h, n_Wo / 8);

    // 2) merged X + Y pure-bf16 GEMMs, 64x128 tiles, XCD swizzle, f32 out
    GJob jx = { e_h, Wo_h,     J, 2 * J, b_out,   ws_X, V, J, MT / 64 };
    GJob jy = { p_h, Wo_h + J, J, 2 * J, nullptr, ws_Y, V, J, MU / 64 };
    const int nbx = (MT / 64) * (V / 128);   // 256
    const int nby = (MU / 64) * (V / 128);   // 64
    gemm64x128<<<nbx + nby, 256, 0, stream>>>(jx, jy, nbx);

    // 3) out = X broadcast + Y (nontemporal stores)
    bcast_kernel<<<dim3(B * T), 256, 0, stream>>>(ws_X, ws_Y, out, T, U);
}